// Round 1
// 4686.951 us; speedup vs baseline: 1.1581x; 1.1581x over previous
//
#include <hip/hip_runtime.h>

// bf16 types
typedef __bf16 bf16;
typedef bf16 bf16x8 __attribute__((ext_vector_type(8)));
typedef float f32x4 __attribute__((ext_vector_type(4)));

__device__ inline bf16x8 bzero8() {
  bf16x8 v;
#pragma unroll
  for (int i = 0; i < 8; ++i) v[i] = (bf16)0.f;
  return v;
}

// async global->LDS, 16B per lane, dest = wave-uniform base + lane*16
__device__ __forceinline__ void gload_lds16(const bf16* g, bf16* l) {
  __builtin_amdgcn_global_load_lds(
      (const __attribute__((address_space(1))) void*)g,
      (__attribute__((address_space(3))) void*)l, 16, 0, 0);
}

#define MFMA16 __builtin_amdgcn_mfma_f32_16x16x32_bf16
#define LGKM0 asm volatile("s_waitcnt lgkmcnt(0)")
#define VMC2 asm volatile("s_waitcnt vmcnt(2)")
#define VMC0 asm volatile("s_waitcnt vmcnt(0)")

// ---------------------------------------------------------------------------
// 256x256-tile, BK=64, 8-wave (2Mx4N), 8-phase counted-vmcnt implicit-GEMM
// conv (m201 template adapted to conv gather).  Per wave: 128x64 output =
// 8x4 f32x4 frags.  LDS: 2 dbuf x {A,B} x 2 halves x [128][64] bf16 = 128KiB.
// Staging: one 128x64 half-tile per phase, 2 x global_load_lds(16B)/thread.
// Swizzle: 16B-chunk XOR (chunk ^= row&7) applied on the per-lane GLOBAL
// source address (LDS dest stays linear for the DMA) and again on ds_read
// (same involution -> reads are bank-conflict-free at the b128 floor).
// vmcnt(2) only at phase 4/8 tails (3 half-tiles in flight), vmcnt(0) only
// at loop edges.  Requirements: M%256==0, N%256==0, K%64==0, CIN in {64,128}
// so each BK=64 window has a single (ky,kx).  A reads in-bounds (zero-halo
// hpad for recurrent convs, VALID geometry for input convs).
//   A[m][k] = in[img][ay+ky][ax+kx][c], img=m/HoWo, k=((ky*5+kx)<<LOG2C)+c
//   B[k][n] = wt[n][k]  (weights pre-transposed to [N][K] bf16)
// epi==0: out_bf[m*N+n] = bf16(acc + bias[n])
// epi==1: out_f[m*N+n]  = acc + xz[((b*T+t)*HoWo+p)*N+n],  m = b*HoWo+p
// ---------------------------------------------------------------------------
template <int CIN, int LOG2C>
__global__ void __launch_bounds__(512, 2)
conv_gemm256(const bf16* __restrict__ in, const bf16* __restrict__ wt,
             const float* __restrict__ bias, const bf16* __restrict__ xz,
             bf16* __restrict__ out_bf, float* __restrict__ out_f,
             int HoWo, int Wo, int inH, int inW,
             int T, int t, int N, int K, int epi)
{
  __shared__ bf16 As[2][2][8192];   // [slot][half][128*64]
  __shared__ bf16 Bs[2][2][8192];

  const int tid  = threadIdx.x;
  const int w    = tid >> 6;
  const int lane = tid & 63;

  // XCD-aware bijective swizzle (m204): contiguous m-chunks per XCD.
  const int gx  = gridDim.x;
  const int nwg = gx * gridDim.y;
  int flat = blockIdx.y * gx + blockIdx.x;
  {
    const int xcd = flat & 7, o = flat >> 3;
    const int qq = nwg >> 3, rr = nwg & 7;
    flat = (xcd < rr ? xcd * (qq + 1) : rr * (qq + 1) + (xcd - rr) * qq) + o;
  }
  const int n0 = (flat % gx) << 8;
  const int m0 = (flat / gx) << 8;

  const long inHW = (long)inH * inW;
  const int lr8  = lane >> 3;                  // staged row & 7
  const int koff = ((lane & 7) ^ lr8) << 3;    // swizzled k elem offset in BK

  // Per-thread staging bases: half h in {0,1}, call j in {0,1}
  long baseA[2][2];
  const bf16* wrowp[2][2];
#pragma unroll
  for (int h = 0; h < 2; ++h)
#pragma unroll
    for (int j = 0; j < 2; ++j) {
      const int row = ((j * 8 + w) << 3) + lr8;     // 0..127 within half
      const int gm  = m0 + h * 128 + row;
      const int img = gm / HoWo;
      const int p   = gm - img * HoWo;
      const int ay  = p / Wo;
      const int ax  = p - ay * Wo;
      baseA[h][j] = ((long)img * inHW + (long)ay * inW + ax) << LOG2C;
      wrowp[h][j] = wt + (long)(n0 + h * 128 + row) * K + koff;
    }

  const int KT = K >> 6;   // number of BK=64 K-tiles (>= 25 for all callers)

  // Stage one 128x64 half-tile of K-tile kt.  half: 0,1 = A halves; 2,3 = B.
  // slot = kt&1.  Wave-uniform LDS dest (linear), per-lane swizzled source.
  auto stage = [&](int kt, int half) {
    if (kt >= KT) return;
    const int slot = kt & 1;
    if (half < 2) {
      const int kk = kt << 6;
      const int kc = kk >> LOG2C;     // uniform over the whole window
      const int ky = kc / 5;
      const int kx = kc - ky * 5;
      const long toff = ((long)(ky * inW + kx) << LOG2C) + (kk & (CIN - 1)) + koff;
      bf16* d = &As[slot][half][w << 9];
      gload_lds16(in + baseA[half][0] + toff, d);
      gload_lds16(in + baseA[half][1] + toff, d + 4096);
    } else {
      const int h = half - 2;
      bf16* d = &Bs[slot][h][w << 9];
      gload_lds16(wrowp[h][0] + (kt << 6), d);
      gload_lds16(wrowp[h][1] + (kt << 6), d + 4096);
    }
  };

  const int lrow = lane & 15;
  const int lq   = lane >> 4;
  const int wm   = w >> 2;     // 0..1 (M)
  const int wn   = w & 3;      // 0..3 (N)
  const int s7   = lrow & 7;

  // Fragment reads with the same XOR involution as the staged source.
  auto rdA = [&](int slot, int r, int ks) -> bf16x8 {
    const int row = (r << 4) + lrow;
    const int ch  = ((ks << 2) + lq) ^ s7;
    return *(const bf16x8*)&As[slot][wm][(row << 6) + (ch << 3)];
  };
  auto rdB = [&](int slot, int cq, int ks) -> bf16x8 {
    const int row = ((wn & 1) << 6) + (cq << 4) + lrow;
    const int ch  = ((ks << 2) + lq) ^ s7;
    return *(const bf16x8*)&Bs[slot][wn >> 1][(row << 6) + (ch << 3)];
  };

  f32x4 acc[8][4];
#pragma unroll
  for (int r = 0; r < 8; ++r)
#pragma unroll
    for (int c = 0; c < 4; ++c) {
      acc[r][c][0] = 0.f; acc[r][c][1] = 0.f;
      acc[r][c][2] = 0.f; acc[r][c][3] = 0.f;
    }

#define QUAD(RB, CB)                                                          \
  __builtin_amdgcn_s_setprio(1);                                              \
  _Pragma("unroll")                                                           \
  for (int r = 0; r < 4; ++r)                                                 \
    _Pragma("unroll")                                                         \
    for (int c = 0; c < 2; ++c) {                                             \
      acc[RB + r][CB + c] =                                                   \
          MFMA16(af[r][0], bq[CB + c][0], acc[RB + r][CB + c], 0, 0, 0);      \
      acc[RB + r][CB + c] =                                                   \
          MFMA16(af[r][1], bq[CB + c][1], acc[RB + r][CB + c], 0, 0, 0);      \
    }                                                                         \
  __builtin_amdgcn_s_setprio(0);

  // Prologue: tile0 fully, tile1 half A0.  Leave tile1-A0's 2 loads in flight.
  stage(0, 0); stage(0, 1); stage(0, 2); stage(0, 3);
  stage(1, 0);
  VMC2;
  __builtin_amdgcn_s_barrier();

  bf16x8 af[4][2], bq[4][2];
  const int NI = KT >> 1;
  for (int i = 0; i < NI; ++i) {
    const int t1 = 2 * i + 1, t2 = 2 * i + 2, t3 = 2 * i + 3;
    // ---- P0: slot0 (r0-3, c0-1); stage t1.A1 -> slot1 ----
#pragma unroll
    for (int r = 0; r < 4; ++r) { af[r][0] = rdA(0, r, 0); af[r][1] = rdA(0, r, 1); }
#pragma unroll
    for (int c = 0; c < 2; ++c) { bq[c][0] = rdB(0, c, 0); bq[c][1] = rdB(0, c, 1); }
    stage(t1, 1);
    __builtin_amdgcn_s_barrier(); LGKM0;
    QUAD(0, 0)
    __builtin_amdgcn_s_barrier();
    // ---- P1: slot0 (r0-3, c2-3); stage t1.B0 ----
#pragma unroll
    for (int c = 2; c < 4; ++c) { bq[c][0] = rdB(0, c, 0); bq[c][1] = rdB(0, c, 1); }
    stage(t1, 2);
    __builtin_amdgcn_s_barrier(); LGKM0;
    QUAD(0, 2)
    __builtin_amdgcn_s_barrier();
    // ---- P2: slot0 (r4-7, c2-3); stage t1.B1 ----
#pragma unroll
    for (int r = 0; r < 4; ++r) { af[r][0] = rdA(0, r + 4, 0); af[r][1] = rdA(0, r + 4, 1); }
    stage(t1, 3);
    __builtin_amdgcn_s_barrier(); LGKM0;
    QUAD(4, 2)
    __builtin_amdgcn_s_barrier();
    // ---- P3: slot0 (r4-7, c0-1); stage t2.A0 -> slot0 (reads done) ----
    stage(t2, 0);
    __builtin_amdgcn_s_barrier(); LGKM0;
    QUAD(4, 0)
    if (t2 < KT) { VMC2; } else { VMC0; }   // t1 fully landed before P4 reads
    __builtin_amdgcn_s_barrier();
    // ---- P4: slot1 (r0-3, c0-1); stage t2.A1 ----
#pragma unroll
    for (int r = 0; r < 4; ++r) { af[r][0] = rdA(1, r, 0); af[r][1] = rdA(1, r, 1); }
#pragma unroll
    for (int c = 0; c < 2; ++c) { bq[c][0] = rdB(1, c, 0); bq[c][1] = rdB(1, c, 1); }
    stage(t2, 1);
    __builtin_amdgcn_s_barrier(); LGKM0;
    QUAD(0, 0)
    __builtin_amdgcn_s_barrier();
    // ---- P5: slot1 (r0-3, c2-3); stage t2.B0 ----
#pragma unroll
    for (int c = 2; c < 4; ++c) { bq[c][0] = rdB(1, c, 0); bq[c][1] = rdB(1, c, 1); }
    stage(t2, 2);
    __builtin_amdgcn_s_barrier(); LGKM0;
    QUAD(0, 2)
    __builtin_amdgcn_s_barrier();
    // ---- P6: slot1 (r4-7, c2-3); stage t2.B1 ----
#pragma unroll
    for (int r = 0; r < 4; ++r) { af[r][0] = rdA(1, r + 4, 0); af[r][1] = rdA(1, r + 4, 1); }
    stage(t2, 3);
    __builtin_amdgcn_s_barrier(); LGKM0;
    QUAD(4, 2)
    __builtin_amdgcn_s_barrier();
    // ---- P7: slot1 (r4-7, c0-1); stage t3.A0 -> slot1 (reads done) ----
    stage(t3, 0);
    __builtin_amdgcn_s_barrier(); LGKM0;
    QUAD(4, 0)
    if (t3 < KT) { VMC2; } else { VMC0; }   // t2 fully landed before next P0
    __builtin_amdgcn_s_barrier();
  }

  // Tail tile for odd KT (tile KT-1, slot0; staged in last iter P3-P6,
  // drained by its P7 VMC0+barrier).  No further staging -> no barriers.
  if (KT & 1) {
#pragma unroll
    for (int r = 0; r < 4; ++r) { af[r][0] = rdA(0, r, 0); af[r][1] = rdA(0, r, 1); }
#pragma unroll
    for (int c = 0; c < 4; ++c) { bq[c][0] = rdB(0, c, 0); bq[c][1] = rdB(0, c, 1); }
    QUAD(0, 0)
    QUAD(0, 2)
#pragma unroll
    for (int r = 0; r < 4; ++r) { af[r][0] = rdA(0, r + 4, 0); af[r][1] = rdA(0, r + 4, 1); }
    QUAD(4, 0)
    QUAD(4, 2)
  }
#undef QUAD

  // Epilogue: C/D layout col=lane&15, row=(lane>>4)*4+reg  [m89-verified]
  const int colb = n0 + wn * 64 + lrow;
  if (epi == 0) {
    float bsv[4];
#pragma unroll
    for (int c = 0; c < 4; ++c) bsv[c] = bias[colb + c * 16];
#pragma unroll
    for (int r = 0; r < 8; ++r)
#pragma unroll
      for (int q = 0; q < 4; ++q) {
        const long row = m0 + wm * 128 + r * 16 + lq * 4 + q;
#pragma unroll
        for (int c = 0; c < 4; ++c)
          out_bf[row * N + colb + c * 16] = (bf16)(acc[r][c][q] + bsv[c]);
      }
  } else {
#pragma unroll
    for (int r = 0; r < 8; ++r)
#pragma unroll
      for (int q = 0; q < 4; ++q) {
        const int row = m0 + wm * 128 + r * 16 + lq * 4 + q;
        const int b   = row / HoWo;
        const int p   = row - b * HoWo;
        const long xrow = (long)(b * T + t) * HoWo + p;
#pragma unroll
        for (int c = 0; c < 4; ++c) {
          const int nn = colb + c * 16;
          out_f[(long)row * N + nn] = acc[r][c][q] + (float)xz[xrow * N + nn];
        }
      }
  }
}

// ---------------------------------------------------------------------------
// Slow 64x64 path — kept ONLY for layer-1 input conv (CIN=5, ragged K=125).
// ---------------------------------------------------------------------------
template <int CIN>
__global__ void __launch_bounds__(256)
conv_gemm64(const bf16* __restrict__ in, const bf16* __restrict__ wt,
            const float* __restrict__ bias, bf16* __restrict__ out_bf,
            int HoWo, int Wo, int inH, int inW, int N, int K)
{
  __shared__ bf16 As[64 * 40];
  __shared__ bf16 Bs[64 * 40];

  const int tid  = threadIdx.x;
  const int wave = tid >> 6;
  const int lane = tid & 63;
  const int m0 = blockIdx.x * 64;
  const int n0 = blockIdx.y * 64;

  const int srow = tid >> 2;
  const int skq  = tid & 3;

  const int am  = m0 + srow;
  const int ab  = am / HoWo;
  const int apx = am - ab * HoWo;
  const int ay  = apx / Wo;
  const int ax  = apx - ay * Wo;
  const long inHW = (long)inH * inW;
  const bf16* inb  = in + (long)ab * inHW * CIN;
  const bf16* wrow = wt + (long)(n0 + srow) * K;

  f32x4 acc[4];
#pragma unroll
  for (int r = 0; r < 4; ++r) { acc[r][0] = 0.f; acc[r][1] = 0.f; acc[r][2] = 0.f; acc[r][3] = 0.f; }

  const int lrow = lane & 15;
  const int lq   = lane >> 4;
  const int ksteps = (K + 31) >> 5;

  for (int ks = 0; ks < ksteps; ++ks) {
    const int k = (ks << 5) + skq * 8;
    bf16x8 av = bzero8(), bv = bzero8();
#pragma unroll
    for (int j = 0; j < 8; ++j) {
      const int ke = k + j;
      if (ke < K) {
        const int c  = ke % CIN;
        const int kc = ke / CIN;
        const int ky = kc / 5;
        const int kx = kc - ky * 5;
        const int iy = ay + ky;
        const int ix = ax + kx;
        av[j] = inb[((long)iy * inW + ix) * CIN + c];
        bv[j] = wrow[ke];
      }
    }
    *(bf16x8*)&As[srow * 40 + skq * 8] = av;
    *(bf16x8*)&Bs[srow * 40 + skq * 8] = bv;
    __syncthreads();

    bf16x8 bfrag = *(const bf16x8*)&Bs[(wave * 16 + lrow) * 40 + lq * 8];
#pragma unroll
    for (int r = 0; r < 4; ++r) {
      bf16x8 afrag = *(const bf16x8*)&As[(r * 16 + lrow) * 40 + lq * 8];
      acc[r] = MFMA16(afrag, bfrag, acc[r], 0, 0, 0);
    }
    __syncthreads();
  }

  const int col = n0 + wave * 16 + lrow;
  const float bsv = bias[col];
#pragma unroll
  for (int r = 0; r < 4; ++r)
#pragma unroll
    for (int q = 0; q < 4; ++q) {
      const long row = m0 + r * 16 + lq * 4 + q;
      out_bf[row * N + col] = (bf16)(acc[r][q] + bsv);
    }
}

// ---------------------------------------------------------------------------
// Fused LSTM gates. Writes h to: hseq (next layer's input, optional),
// hpad (zero-halo padded buffer for next timestep's recurrent conv, optional),
// hf (fp32 final h for dense head, optional).
// ---------------------------------------------------------------------------
__global__ void __launch_bounds__(256)
gate_kernel(const bf16* __restrict__ xz, const float* __restrict__ hz,
            float* __restrict__ c, bf16* __restrict__ hseq,
            bf16* __restrict__ hpad, float* __restrict__ hf,
            int HoWo, int Wo, int Wp, int HpWp, int F, int t, int T, int total)
{
  const int idx = blockIdx.x * 256 + threadIdx.x;
  if (idx >= total) return;
  const int f  = idx % F;
  const int bp = idx / F;            // b*HoWo + p
  const int b  = bp / HoWo;
  const int p  = bp - b * HoWo;
  const int N4 = 4 * F;

  float zi, zf, zc, zo;
  if (hz != nullptr) {
    const float* zp = hz + (long)bp * N4 + f;
    zi = zp[0]; zf = zp[F]; zc = zp[2 * F]; zo = zp[3 * F];
  } else {
    const bf16* zp = xz + ((long)(b * T + t) * HoWo + p) * N4 + f;
    zi = (float)zp[0]; zf = (float)zp[F]; zc = (float)zp[2 * F]; zo = (float)zp[3 * F];
  }
  const float cprev = (t > 0) ? c[idx] : 0.f;
  const float ig = fminf(fmaxf(0.2f * zi + 0.5f, 0.f), 1.f);
  const float fg = fminf(fmaxf(0.2f * zf + 0.5f, 0.f), 1.f);
  const float og = fminf(fmaxf(0.2f * zo + 0.5f, 0.f), 1.f);
  const float cn = fg * cprev + ig * tanhf(zc);
  const float h  = og * tanhf(cn);
  c[idx] = cn;
  const bf16 hb = (bf16)h;
  if (hseq != nullptr)
    hseq[((long)(b * T + t) * HoWo + p) * F + f] = hb;
  if (hpad != nullptr) {
    const int y = p / Wo;
    const int x = p - y * Wo;
    hpad[((long)b * HpWp + (long)(y + 2) * Wp + (x + 2)) * F + f] = hb;
  }
  if (hf != nullptr) hf[idx] = h;
}

// ---------------------------------------------------------------------------
__global__ void __launch_bounds__(256)
cast_f32_bf16(const float* __restrict__ in, bf16* __restrict__ out, int n)
{
  const int i = blockIdx.x * 256 + threadIdx.x;
  if (i < n) out[i] = (bf16)in[i];
}

// weights (K,N) fp32 -> (N,K) bf16
__global__ void __launch_bounds__(256)
cast_transpose(const float* __restrict__ in, bf16* __restrict__ out, int K, int N)
{
  const int i = blockIdx.x * 256 + threadIdx.x;
  if (i < K * N) {
    const int k = i / N;
    const int n = i - k * N;
    out[(long)n * K + k] = (bf16)in[i];
  }
}

// ---------------------------------------------------------------------------
__global__ void __launch_bounds__(256)
dense_splitk(const float* __restrict__ A, const float* __restrict__ W,
             float* __restrict__ out, int D, int N, int chunk)
{
  const int j  = blockIdx.x * 256 + threadIdx.x;
  const int d0 = blockIdx.y * chunk;
  int d1 = d0 + chunk; if (d1 > D) d1 = D;
  float acc[16];
#pragma unroll
  for (int b = 0; b < 16; ++b) acc[b] = 0.f;
  for (int d = d0; d < d1; ++d) {
    const float w = W[(long)d * N + j];
#pragma unroll
    for (int b = 0; b < 16; ++b) acc[b] += A[(long)b * D + d] * w;
  }
#pragma unroll
  for (int b = 0; b < 16; ++b) atomicAdd(&out[b * N + j], acc[b]);
}

__global__ void __launch_bounds__(256)
bias_relu(const float* __restrict__ in, const float* __restrict__ bias,
          float* __restrict__ out, int N, int total)
{
  const int i = blockIdx.x * 256 + threadIdx.x;
  if (i < total) {
    const int j = i % N;
    const float v = in[i] + bias[j];
    out[i] = v > 0.f ? v : 0.f;
  }
}

__global__ void __launch_bounds__(256)
dense3_kernel(const float* __restrict__ z, const float* __restrict__ W,
              const float* __restrict__ bias, float* __restrict__ out)
{
  const int b = blockIdx.x;
  const int tid = threadIdx.x;
  float a0 = 0.f, a1 = 0.f, a2 = 0.f, a3 = 0.f;
  for (int d = tid; d < 1024; d += 256) {
    const float zv = z[b * 1024 + d];
    a0 += zv * W[d * 4 + 0]; a1 += zv * W[d * 4 + 1];
    a2 += zv * W[d * 4 + 2]; a3 += zv * W[d * 4 + 3];
  }
  __shared__ float red[256][4];
  red[tid][0] = a0; red[tid][1] = a1; red[tid][2] = a2; red[tid][3] = a3;
  __syncthreads();
  for (int s = 128; s > 0; s >>= 1) {
    if (tid < s) {
      red[tid][0] += red[tid + s][0]; red[tid][1] += red[tid + s][1];
      red[tid][2] += red[tid + s][2]; red[tid][3] += red[tid + s][3];
    }
    __syncthreads();
  }
  if (tid < 4) out[b * 4 + tid] = red[0][tid] + bias[tid];
}

// ---------------------------------------------------------------------------
extern "C" void kernel_launch(void* const* d_in, const int* in_sizes, int n_in,
                              void* d_out, int out_size, void* d_ws, size_t ws_size,
                              hipStream_t stream)
{
  const float* x   = (const float*)d_in[0];
  const float* Wx1 = (const float*)d_in[1];
  const float* Wh1 = (const float*)d_in[2];
  const float* b1  = (const float*)d_in[3];
  const float* Wx2 = (const float*)d_in[4];
  const float* Wh2 = (const float*)d_in[5];
  const float* b2  = (const float*)d_in[6];
  const float* Wx3 = (const float*)d_in[7];
  const float* Wh3 = (const float*)d_in[8];
  const float* b3  = (const float*)d_in[9];
  const float* Wd1 = (const float*)d_in[10];
  const float* bd1 = (const float*)d_in[11];
  const float* Wd2 = (const float*)d_in[12];
  const float* bd2 = (const float*)d_in[13];
  const float* Wd3 = (const float*)d_in[14];
  const float* bd3 = (const float*)d_in[15];

  char* ws = (char*)d_ws;
  size_t off = 0;
  auto alloc = [&](size_t bytes) -> void* {
    void* p = ws + off;
    off += (bytes + 255) & ~(size_t)255;
    return p;
  };
  bf16* x_bf = (bf16*)alloc((size_t)1966080 * 2);
  bf16* wx1t = (bf16*)alloc((size_t)64000 * 2);     // [512][125]
  bf16* wh1t = (bf16*)alloc((size_t)1638400 * 2);   // [512][3200]
  bf16* wx2t = (bf16*)alloc((size_t)819200 * 2);    // [256][3200]
  bf16* wh2t = (bf16*)alloc((size_t)409600 * 2);    // [256][1600]
  bf16* wx3t = (bf16*)alloc((size_t)409600 * 2);    // [256][1600]
  bf16* wh3t = (bf16*)alloc((size_t)409600 * 2);    // [256][1600]
  bf16* xzA  = (bf16*)alloc((size_t)176947200 * 2); // xz1 (354MB) | xz2 | xz3
  bf16* hB   = (bf16*)alloc((size_t)44236800 * 2);  // h1seq | h2seq
  float* hzC = (float*)alloc((size_t)29491200 * 4); // hz1 (118MB) | hz2 | hz3
  float* cA  = (float*)alloc((size_t)7372800 * 4);  // c1 | (c2,c3)
  float* h3f = (float*)alloc((size_t)2768896 * 4);
  bf16* hpadA = (bf16*)alloc((size_t)8388608 * 2);  // hpad1 | (hpad2,hpad3)
  float* out1 = (float*)alloc(16384 * 4);
  float* z1   = (float*)alloc(16384 * 4);
  float* out2 = (float*)alloc(16384 * 4);
  float* z2   = (float*)alloc(16384 * 4);

  bf16* h1seq = hB;
  bf16* h2seq = hB;                       // h1seq dead once xz2 built
  float* c1 = cA;
  float* c2 = cA;                         // c1 dead after layer 1
  float* c3 = cA + (size_t)3211264;
  bf16* hpad1 = hpadA;                    // [16][64][64][128]
  bf16* hpad2 = hpadA;                    // [16][60][60][64], after layer 1
  bf16* hpad3 = hpadA + (size_t)3686400;  // [16][56][56][64]

  // ---- weight/input casts ----
  cast_f32_bf16<<<(1966080 + 255) / 256, 256, 0, stream>>>(x, x_bf, 1966080);
  cast_transpose<<<(64000 + 255) / 256, 256, 0, stream>>>(Wx1, wx1t, 125, 512);
  cast_transpose<<<(1638400 + 255) / 256, 256, 0, stream>>>(Wh1, wh1t, 3200, 512);
  cast_transpose<<<(819200 + 255) / 256, 256, 0, stream>>>(Wx2, wx2t, 3200, 256);
  cast_transpose<<<(409600 + 255) / 256, 256, 0, stream>>>(Wh2, wh2t, 1600, 256);
  cast_transpose<<<(409600 + 255) / 256, 256, 0, stream>>>(Wx3, wx3t, 1600, 256);
  cast_transpose<<<(409600 + 255) / 256, 256, 0, stream>>>(Wh3, wh3t, 1600, 256);

  // ---- layer 1: 64x64x5 -> 60x60x128, N=512 ----
  hipMemsetAsync(hpadA, 0, (size_t)8388608 * 2, stream);  // zero halo (whole buf)
  conv_gemm64<5><<<dim3(5400, 8), 256, 0, stream>>>(
      x_bf, wx1t, b1, xzA, 3600, 60, 64, 64, 512, 125);
  for (int t = 0; t < 6; ++t) {
    if (t > 0)
      conv_gemm256<128, 7><<<dim3(2, 225), 512, 0, stream>>>(
          hpad1, wh1t, nullptr, xzA, nullptr, hzC,
          3600, 60, 64, 64, 6, t, 512, 3200, 1);
    gate_kernel<<<28800, 256, 0, stream>>>(
        xzA, (t > 0) ? hzC : nullptr, c1, h1seq,
        (t < 5) ? hpad1 : nullptr, nullptr,
        3600, 60, 64, 4096, 128, t, 6, 7372800);
  }

  // ---- layer 2: 60x60x128 -> 56x56x64, N=256 ----
  bf16* xz2 = xzA;
  conv_gemm256<128, 7><<<dim3(1, 1176), 512, 0, stream>>>(
      h1seq, wx2t, b2, nullptr, xz2, nullptr,
      3136, 56, 60, 60, 6, 0, 256, 3200, 0);
  hipMemsetAsync(hpad2, 0, (size_t)3686400 * 2, stream);
  for (int t = 0; t < 6; ++t) {
    if (t > 0)
      conv_gemm256<64, 6><<<dim3(1, 196), 512, 0, stream>>>(
          hpad2, wh2t, nullptr, xz2, nullptr, hzC,
          3136, 56, 60, 60, 6, t, 256, 1600, 1);
    gate_kernel<<<12544, 256, 0, stream>>>(
        xz2, (t > 0) ? hzC : nullptr, c2, h2seq,
        (t < 5) ? hpad2 : nullptr, nullptr,
        3136, 56, 60, 3600, 64, t, 6, 3211264);
  }

  // ---- layer 3: 56x56x64 -> 52x52x64, N=256, return last h only ----
  bf16* xz3 = xzA;
  conv_gemm256<64, 6><<<dim3(1, 1014), 512, 0, stream>>>(
      h2seq, wx3t, b3, nullptr, xz3, nullptr,
      2704, 52, 56, 56, 6, 0, 256, 1600, 0);
  hipMemsetAsync(hpad3, 0, (size_t)3211264 * 2, stream);
  for (int t = 0; t < 6; ++t) {
    if (t > 0)
      conv_gemm256<64, 6><<<dim3(1, 169), 512, 0, stream>>>(
          hpad3, wh3t, nullptr, xz3, nullptr, hzC,
          2704, 52, 56, 56, 6, t, 256, 1600, 1);
    gate_kernel<<<10816, 256, 0, stream>>>(
        xz3, (t > 0) ? hzC : nullptr, c3, nullptr,
        (t < 5) ? hpad3 : nullptr, (t == 5) ? h3f : nullptr,
        2704, 52, 56, 3136, 64, t, 6, 2768896);
  }

  // ---- dense head (fp32) ----
  hipMemsetAsync(out1, 0, 16384 * 4, stream);
  hipMemsetAsync(out2, 0, 16384 * 4, stream);
  dense_splitk<<<dim3(4, 169), 256, 0, stream>>>(h3f, Wd1, out1, 173056, 1024, 1024);
  bias_relu<<<64, 256, 0, stream>>>(out1, bd1, z1, 1024, 16384);
  dense_splitk<<<dim3(4, 4), 256, 0, stream>>>(z1, Wd2, out2, 1024, 1024, 256);
  bias_relu<<<64, 256, 0, stream>>>(out2, bd2, z2, 1024, 16384);
  dense3_kernel<<<16, 256, 0, stream>>>(z2, Wd3, bd3, (float*)d_out);
}

// Round 2
// 4390.493 us; speedup vs baseline: 1.2363x; 1.0675x over previous
//
#include <hip/hip_runtime.h>

// bf16 types
typedef __bf16 bf16;
typedef bf16 bf16x8 __attribute__((ext_vector_type(8)));
typedef float f32x4 __attribute__((ext_vector_type(4)));

__device__ inline bf16x8 bzero8() {
  bf16x8 v;
#pragma unroll
  for (int i = 0; i < 8; ++i) v[i] = (bf16)0.f;
  return v;
}

// async global->LDS, 16B per lane, dest = wave-uniform base + lane*16
__device__ __forceinline__ void gload_lds16(const bf16* g, bf16* l) {
  __builtin_amdgcn_global_load_lds(
      (const __attribute__((address_space(1))) void*)g,
      (__attribute__((address_space(3))) void*)l, 16, 0, 0);
}

#define MFMA16 __builtin_amdgcn_mfma_f32_16x16x32_bf16
#define LGKM0 asm volatile("s_waitcnt lgkmcnt(0)")
#define VMC2 asm volatile("s_waitcnt vmcnt(2)")
#define VMC0 asm volatile("s_waitcnt vmcnt(0)")

// ---------------------------------------------------------------------------
// 256x256-tile, BK=64, 8-wave (2Mx4N), 8-phase counted-vmcnt implicit-GEMM
// conv (m201 template adapted to conv gather).  Per wave: 128x64 output =
// 8x4 f32x4 frags.  LDS: 2 dbuf x {A,B} x 2 halves x [128][64] bf16 = 128KiB.
// Staging: one 128x64 half-tile per phase, 2 x global_load_lds(16B)/thread.
// Swizzle: 16B-chunk XOR (chunk ^= row&7) applied on the per-lane GLOBAL
// source address (LDS dest stays linear for the DMA) and again on ds_read
// (same involution -> reads are bank-conflict-free at the b128 floor).
// vmcnt(2) only at phase 4/8 tails (3 half-tiles in flight), vmcnt(0) only
// at loop edges.  Requirements: M%256==0, N%256==0, K%64==0, CIN in {64,128}
// so each BK=64 window has a single (ky,kx).  A reads in-bounds (zero-halo
// hpad for recurrent convs, VALID geometry for input convs).
//   A[m][k] = in[img][ay+ky][ax+kx][c], img=m/HoWo, k=((ky*5+kx)<<LOG2C)+c
//   B[k][n] = wt[n][k]  (weights pre-transposed to [N][K] bf16)
// epi==0: out_bf[m*N+n] = bf16(acc + bias[n])
// epi==1: out_f[m*N+n]  = acc + xz[((b*T+t)*HoWo+p)*N+n],  m = b*HoWo+p
// ---------------------------------------------------------------------------
template <int CIN, int LOG2C>
__global__ void __launch_bounds__(512, 2)
conv_gemm256(const bf16* __restrict__ in, const bf16* __restrict__ wt,
             const float* __restrict__ bias, const bf16* __restrict__ xz,
             bf16* __restrict__ out_bf, float* __restrict__ out_f,
             int HoWo, int Wo, int inH, int inW,
             int T, int t, int N, int K, int epi)
{
  __shared__ bf16 As[2][2][8192];   // [slot][half][128*64]
  __shared__ bf16 Bs[2][2][8192];

  const int tid  = threadIdx.x;
  const int w    = tid >> 6;
  const int lane = tid & 63;

  // XCD-aware bijective swizzle (m204): contiguous m-chunks per XCD.
  const int gx  = gridDim.x;
  const int nwg = gx * gridDim.y;
  int flat = blockIdx.y * gx + blockIdx.x;
  {
    const int xcd = flat & 7, o = flat >> 3;
    const int qq = nwg >> 3, rr = nwg & 7;
    flat = (xcd < rr ? xcd * (qq + 1) : rr * (qq + 1) + (xcd - rr) * qq) + o;
  }
  const int n0 = (flat % gx) << 8;
  const int m0 = (flat / gx) << 8;

  const long inHW = (long)inH * inW;
  const int lr8  = lane >> 3;                  // staged row & 7
  const int koff = ((lane & 7) ^ lr8) << 3;    // swizzled k elem offset in BK

  // Per-thread staging bases: half h in {0,1}, call j in {0,1}
  long baseA[2][2];
  const bf16* wrowp[2][2];
#pragma unroll
  for (int h = 0; h < 2; ++h)
#pragma unroll
    for (int j = 0; j < 2; ++j) {
      const int row = ((j * 8 + w) << 3) + lr8;     // 0..127 within half
      const int gm  = m0 + h * 128 + row;
      const int img = gm / HoWo;
      const int p   = gm - img * HoWo;
      const int ay  = p / Wo;
      const int ax  = p - ay * Wo;
      baseA[h][j] = ((long)img * inHW + (long)ay * inW + ax) << LOG2C;
      wrowp[h][j] = wt + (long)(n0 + h * 128 + row) * K + koff;
    }

  const int KT = K >> 6;   // number of BK=64 K-tiles (>= 25 for all callers)

  // Stage one 128x64 half-tile of K-tile kt.  half: 0,1 = A halves; 2,3 = B.
  // slot = kt&1.  Wave-uniform LDS dest (linear), per-lane swizzled source.
  auto stage = [&](int kt, int half) {
    if (kt >= KT) return;
    const int slot = kt & 1;
    if (half < 2) {
      const int kk = kt << 6;
      const int kc = kk >> LOG2C;     // uniform over the whole window
      const int ky = kc / 5;
      const int kx = kc - ky * 5;
      const long toff = ((long)(ky * inW + kx) << LOG2C) + (kk & (CIN - 1)) + koff;
      bf16* d = &As[slot][half][w << 9];
      gload_lds16(in + baseA[half][0] + toff, d);
      gload_lds16(in + baseA[half][1] + toff, d + 4096);
    } else {
      const int h = half - 2;
      bf16* d = &Bs[slot][h][w << 9];
      gload_lds16(wrowp[h][0] + (kt << 6), d);
      gload_lds16(wrowp[h][1] + (kt << 6), d + 4096);
    }
  };

  const int lrow = lane & 15;
  const int lq   = lane >> 4;
  const int wm   = w >> 2;     // 0..1 (M)
  const int wn   = w & 3;      // 0..3 (N)
  const int s7   = lrow & 7;

  // Fragment reads with the same XOR involution as the staged source.
  auto rdA = [&](int slot, int r, int ks) -> bf16x8 {
    const int row = (r << 4) + lrow;
    const int ch  = ((ks << 2) + lq) ^ s7;
    return *(const bf16x8*)&As[slot][wm][(row << 6) + (ch << 3)];
  };
  auto rdB = [&](int slot, int cq, int ks) -> bf16x8 {
    const int row = ((wn & 1) << 6) + (cq << 4) + lrow;
    const int ch  = ((ks << 2) + lq) ^ s7;
    return *(const bf16x8*)&Bs[slot][wn >> 1][(row << 6) + (ch << 3)];
  };

  f32x4 acc[8][4];
#pragma unroll
  for (int r = 0; r < 8; ++r)
#pragma unroll
    for (int c = 0; c < 4; ++c) {
      acc[r][c][0] = 0.f; acc[r][c][1] = 0.f;
      acc[r][c][2] = 0.f; acc[r][c][3] = 0.f;
    }

#define QUAD(RB, CB)                                                          \
  __builtin_amdgcn_s_setprio(1);                                              \
  _Pragma("unroll")                                                           \
  for (int r = 0; r < 4; ++r)                                                 \
    _Pragma("unroll")                                                         \
    for (int c = 0; c < 2; ++c) {                                             \
      acc[RB + r][CB + c] =                                                   \
          MFMA16(af[r][0], bq[CB + c][0], acc[RB + r][CB + c], 0, 0, 0);      \
      acc[RB + r][CB + c] =                                                   \
          MFMA16(af[r][1], bq[CB + c][1], acc[RB + r][CB + c], 0, 0, 0);      \
    }                                                                         \
  __builtin_amdgcn_s_setprio(0);

  // Prologue: tile0 fully, tile1 half A0.  Leave tile1-A0's 2 loads in flight.
  stage(0, 0); stage(0, 1); stage(0, 2); stage(0, 3);
  stage(1, 0);
  VMC2;
  __builtin_amdgcn_s_barrier();

  bf16x8 af[4][2], bq[4][2];
  const int NI = KT >> 1;
  for (int i = 0; i < NI; ++i) {
    const int t1 = 2 * i + 1, t2 = 2 * i + 2, t3 = 2 * i + 3;
    // ---- P0: slot0 (r0-3, c0-1); stage t1.A1 -> slot1 ----
#pragma unroll
    for (int r = 0; r < 4; ++r) { af[r][0] = rdA(0, r, 0); af[r][1] = rdA(0, r, 1); }
#pragma unroll
    for (int c = 0; c < 2; ++c) { bq[c][0] = rdB(0, c, 0); bq[c][1] = rdB(0, c, 1); }
    stage(t1, 1);
    __builtin_amdgcn_s_barrier(); LGKM0;
    QUAD(0, 0)
    __builtin_amdgcn_s_barrier();
    // ---- P1: slot0 (r0-3, c2-3); stage t1.B0 ----
#pragma unroll
    for (int c = 2; c < 4; ++c) { bq[c][0] = rdB(0, c, 0); bq[c][1] = rdB(0, c, 1); }
    stage(t1, 2);
    __builtin_amdgcn_s_barrier(); LGKM0;
    QUAD(0, 2)
    __builtin_amdgcn_s_barrier();
    // ---- P2: slot0 (r4-7, c2-3); stage t1.B1 ----
#pragma unroll
    for (int r = 0; r < 4; ++r) { af[r][0] = rdA(0, r + 4, 0); af[r][1] = rdA(0, r + 4, 1); }
    stage(t1, 3);
    __builtin_amdgcn_s_barrier(); LGKM0;
    QUAD(4, 2)
    __builtin_amdgcn_s_barrier();
    // ---- P3: slot0 (r4-7, c0-1); stage t2.A0 -> slot0 (reads done) ----
    stage(t2, 0);
    __builtin_amdgcn_s_barrier(); LGKM0;
    QUAD(4, 0)
    if (t2 < KT) { VMC2; } else { VMC0; }   // t1 fully landed before P4 reads
    __builtin_amdgcn_s_barrier();
    // ---- P4: slot1 (r0-3, c0-1); stage t2.A1 ----
#pragma unroll
    for (int r = 0; r < 4; ++r) { af[r][0] = rdA(1, r, 0); af[r][1] = rdA(1, r, 1); }
#pragma unroll
    for (int c = 0; c < 2; ++c) { bq[c][0] = rdB(1, c, 0); bq[c][1] = rdB(1, c, 1); }
    stage(t2, 1);
    __builtin_amdgcn_s_barrier(); LGKM0;
    QUAD(0, 0)
    __builtin_amdgcn_s_barrier();
    // ---- P5: slot1 (r0-3, c2-3); stage t2.B0 ----
#pragma unroll
    for (int c = 2; c < 4; ++c) { bq[c][0] = rdB(1, c, 0); bq[c][1] = rdB(1, c, 1); }
    stage(t2, 2);
    __builtin_amdgcn_s_barrier(); LGKM0;
    QUAD(0, 2)
    __builtin_amdgcn_s_barrier();
    // ---- P6: slot1 (r4-7, c2-3); stage t2.B1 ----
#pragma unroll
    for (int r = 0; r < 4; ++r) { af[r][0] = rdA(1, r + 4, 0); af[r][1] = rdA(1, r + 4, 1); }
    stage(t2, 3);
    __builtin_amdgcn_s_barrier(); LGKM0;
    QUAD(4, 2)
    __builtin_amdgcn_s_barrier();
    // ---- P7: slot1 (r4-7, c0-1); stage t3.A0 -> slot1 (reads done) ----
    stage(t3, 0);
    __builtin_amdgcn_s_barrier(); LGKM0;
    QUAD(4, 0)
    if (t3 < KT) { VMC2; } else { VMC0; }   // t2 fully landed before next P0
    __builtin_amdgcn_s_barrier();
  }

  // Tail tile for odd KT (tile KT-1, slot0; staged in last iter P3-P6,
  // drained by its P7 VMC0+barrier).  No further staging -> no barriers.
  if (KT & 1) {
#pragma unroll
    for (int r = 0; r < 4; ++r) { af[r][0] = rdA(0, r, 0); af[r][1] = rdA(0, r, 1); }
#pragma unroll
    for (int c = 0; c < 4; ++c) { bq[c][0] = rdB(0, c, 0); bq[c][1] = rdB(0, c, 1); }
    QUAD(0, 0)
    QUAD(0, 2)
#pragma unroll
    for (int r = 0; r < 4; ++r) { af[r][0] = rdA(0, r + 4, 0); af[r][1] = rdA(0, r + 4, 1); }
    QUAD(4, 0)
    QUAD(4, 2)
  }
#undef QUAD

  // Epilogue: C/D layout col=lane&15, row=(lane>>4)*4+reg  [m89-verified]
  const int colb = n0 + wn * 64 + lrow;
  if (epi == 0) {
    float bsv[4];
#pragma unroll
    for (int c = 0; c < 4; ++c) bsv[c] = bias[colb + c * 16];
#pragma unroll
    for (int r = 0; r < 8; ++r)
#pragma unroll
      for (int q = 0; q < 4; ++q) {
        const long row = m0 + wm * 128 + r * 16 + lq * 4 + q;
#pragma unroll
        for (int c = 0; c < 4; ++c)
          out_bf[row * N + colb + c * 16] = (bf16)(acc[r][c][q] + bsv[c]);
      }
  } else {
#pragma unroll
    for (int r = 0; r < 8; ++r)
#pragma unroll
      for (int q = 0; q < 4; ++q) {
        const int row = m0 + wm * 128 + r * 16 + lq * 4 + q;
        const int b   = row / HoWo;
        const int p   = row - b * HoWo;
        const long xrow = (long)(b * T + t) * HoWo + p;
#pragma unroll
        for (int c = 0; c < 4; ++c) {
          const int nn = colb + c * 16;
          out_f[(long)row * N + nn] = acc[r][c][q] + (float)xz[xrow * N + nn];
        }
      }
  }
}

// ---------------------------------------------------------------------------
// Slow 64x64 path — kept ONLY for layer-1 input conv (CIN=5, ragged K=125).
// ---------------------------------------------------------------------------
template <int CIN>
__global__ void __launch_bounds__(256)
conv_gemm64(const bf16* __restrict__ in, const bf16* __restrict__ wt,
            const float* __restrict__ bias, bf16* __restrict__ out_bf,
            int HoWo, int Wo, int inH, int inW, int N, int K)
{
  __shared__ bf16 As[64 * 40];
  __shared__ bf16 Bs[64 * 40];

  const int tid  = threadIdx.x;
  const int wave = tid >> 6;
  const int lane = tid & 63;
  const int m0 = blockIdx.x * 64;
  const int n0 = blockIdx.y * 64;

  const int srow = tid >> 2;
  const int skq  = tid & 3;

  const int am  = m0 + srow;
  const int ab  = am / HoWo;
  const int apx = am - ab * HoWo;
  const int ay  = apx / Wo;
  const int ax  = apx - ay * Wo;
  const long inHW = (long)inH * inW;
  const bf16* inb  = in + (long)ab * inHW * CIN;
  const bf16* wrow = wt + (long)(n0 + srow) * K;

  f32x4 acc[4];
#pragma unroll
  for (int r = 0; r < 4; ++r) { acc[r][0] = 0.f; acc[r][1] = 0.f; acc[r][2] = 0.f; acc[r][3] = 0.f; }

  const int lrow = lane & 15;
  const int lq   = lane >> 4;
  const int ksteps = (K + 31) >> 5;

  for (int ks = 0; ks < ksteps; ++ks) {
    const int k = (ks << 5) + skq * 8;
    bf16x8 av = bzero8(), bv = bzero8();
#pragma unroll
    for (int j = 0; j < 8; ++j) {
      const int ke = k + j;
      if (ke < K) {
        const int c  = ke % CIN;
        const int kc = ke / CIN;
        const int ky = kc / 5;
        const int kx = kc - ky * 5;
        const int iy = ay + ky;
        const int ix = ax + kx;
        av[j] = inb[((long)iy * inW + ix) * CIN + c];
        bv[j] = wrow[ke];
      }
    }
    *(bf16x8*)&As[srow * 40 + skq * 8] = av;
    *(bf16x8*)&Bs[srow * 40 + skq * 8] = bv;
    __syncthreads();

    bf16x8 bfrag = *(const bf16x8*)&Bs[(wave * 16 + lrow) * 40 + lq * 8];
#pragma unroll
    for (int r = 0; r < 4; ++r) {
      bf16x8 afrag = *(const bf16x8*)&As[(r * 16 + lrow) * 40 + lq * 8];
      acc[r] = MFMA16(afrag, bfrag, acc[r], 0, 0, 0);
    }
    __syncthreads();
  }

  const int col = n0 + wave * 16 + lrow;
  const float bsv = bias[col];
#pragma unroll
  for (int r = 0; r < 4; ++r)
#pragma unroll
    for (int q = 0; q < 4; ++q) {
      const long row = m0 + r * 16 + lq * 4 + q;
      out_bf[row * N + col] = (bf16)(acc[r][q] + bsv);
    }
}

// ---------------------------------------------------------------------------
// Fused LSTM gates. Writes h to: hseq (next layer's input, optional),
// hpad (zero-halo padded buffer for next timestep's recurrent conv, optional),
// hf (fp32 final h for dense head, optional).
// ---------------------------------------------------------------------------
__global__ void __launch_bounds__(256)
gate_kernel(const bf16* __restrict__ xz, const float* __restrict__ hz,
            float* __restrict__ c, bf16* __restrict__ hseq,
            bf16* __restrict__ hpad, float* __restrict__ hf,
            int HoWo, int Wo, int Wp, int HpWp, int F, int t, int T, int total)
{
  const int idx = blockIdx.x * 256 + threadIdx.x;
  if (idx >= total) return;
  const int f  = idx % F;
  const int bp = idx / F;            // b*HoWo + p
  const int b  = bp / HoWo;
  const int p  = bp - b * HoWo;
  const int N4 = 4 * F;

  float zi, zf, zc, zo;
  if (hz != nullptr) {
    const float* zp = hz + (long)bp * N4 + f;
    zi = zp[0]; zf = zp[F]; zc = zp[2 * F]; zo = zp[3 * F];
  } else {
    const bf16* zp = xz + ((long)(b * T + t) * HoWo + p) * N4 + f;
    zi = (float)zp[0]; zf = (float)zp[F]; zc = (float)zp[2 * F]; zo = (float)zp[3 * F];
  }
  const float cprev = (t > 0) ? c[idx] : 0.f;
  const float ig = fminf(fmaxf(0.2f * zi + 0.5f, 0.f), 1.f);
  const float fg = fminf(fmaxf(0.2f * zf + 0.5f, 0.f), 1.f);
  const float og = fminf(fmaxf(0.2f * zo + 0.5f, 0.f), 1.f);
  const float cn = fg * cprev + ig * tanhf(zc);
  const float h  = og * tanhf(cn);
  c[idx] = cn;
  const bf16 hb = (bf16)h;
  if (hseq != nullptr)
    hseq[((long)(b * T + t) * HoWo + p) * F + f] = hb;
  if (hpad != nullptr) {
    const int y = p / Wo;
    const int x = p - y * Wo;
    hpad[((long)b * HpWp + (long)(y + 2) * Wp + (x + 2)) * F + f] = hb;
  }
  if (hf != nullptr) hf[idx] = h;
}

// ---------------------------------------------------------------------------
__global__ void __launch_bounds__(256)
cast_f32_bf16(const float* __restrict__ in, bf16* __restrict__ out, int n)
{
  const int i = blockIdx.x * 256 + threadIdx.x;
  if (i < n) out[i] = (bf16)in[i];
}

// weights (K,N) fp32 -> (N,K) bf16
__global__ void __launch_bounds__(256)
cast_transpose(const float* __restrict__ in, bf16* __restrict__ out, int K, int N)
{
  const int i = blockIdx.x * 256 + threadIdx.x;
  if (i < K * N) {
    const int k = i / N;
    const int n = i - k * N;
    out[(long)n * K + k] = (bf16)in[i];
  }
}

// ---------------------------------------------------------------------------
// Dense layer 1/2: skinny GEMM (16 x D) @ (D x 1024), HBM-bound on W.
// Stage 1: G blocks (1/CU for layer 1), each reduces `chunk` rows of W into
// per-block partials part[g][16][1024].  Each thread owns 4 consecutive cols
// (float4 W loads, coalesced 4KB row per block); d-loop unrolled x4 so 4
// float4 loads are in flight (64B/thread in-flight covers HBM latency).
// A-row reads are loop-uniform -> scalar path / L1 broadcast.
// Stage 2 (dense_reduce): out[b][j] = relu(bias[j] + sum_g part[g][b][j]).
// ---------------------------------------------------------------------------
__global__ void __launch_bounds__(256)
dense_stage1(const float* __restrict__ A, const float* __restrict__ W,
             float* __restrict__ part, int D, int chunk)
{
  const int tid = threadIdx.x;
  const int j4  = tid << 2;            // 4 cols per thread; N = 1024 fixed
  const int g   = blockIdx.x;
  const int d0  = g * chunk;
  int d1 = d0 + chunk; if (d1 > D) d1 = D;

  f32x4 acc[16];
#pragma unroll
  for (int b = 0; b < 16; ++b) {
    acc[b][0] = 0.f; acc[b][1] = 0.f; acc[b][2] = 0.f; acc[b][3] = 0.f;
  }

  for (int d = d0; d < d1; d += 4) {   // chunk % 4 == 0 for all callers
#pragma unroll
    for (int u = 0; u < 4; ++u) {
      const f32x4 w4 = *(const f32x4*)&W[(long)(d + u) * 1024 + j4];
#pragma unroll
      for (int b = 0; b < 16; ++b) {
        const float a = A[(long)b * D + d + u];
        acc[b][0] += a * w4[0]; acc[b][1] += a * w4[1];
        acc[b][2] += a * w4[2]; acc[b][3] += a * w4[3];
      }
    }
  }

  float* po = part + ((long)g << 14);  // 16*1024 floats per block
#pragma unroll
  for (int b = 0; b < 16; ++b)
    *(f32x4*)&po[(b << 10) + j4] = acc[b];
}

__global__ void __launch_bounds__(256)
dense_reduce(const float* __restrict__ part, const float* __restrict__ bias,
             float* __restrict__ out, int G)
{
  const int i = blockIdx.x * 256 + threadIdx.x;   // 16384 outputs
  const int j = i & 1023;
  float s = bias[j];
#pragma unroll 4
  for (int g = 0; g < G; ++g) s += part[((long)g << 14) + i];
  out[i] = s > 0.f ? s : 0.f;
}

__global__ void __launch_bounds__(256)
dense3_kernel(const float* __restrict__ z, const float* __restrict__ W,
              const float* __restrict__ bias, float* __restrict__ out)
{
  const int b = blockIdx.x;
  const int tid = threadIdx.x;
  float a0 = 0.f, a1 = 0.f, a2 = 0.f, a3 = 0.f;
  for (int d = tid; d < 1024; d += 256) {
    const float zv = z[b * 1024 + d];
    a0 += zv * W[d * 4 + 0]; a1 += zv * W[d * 4 + 1];
    a2 += zv * W[d * 4 + 2]; a3 += zv * W[d * 4 + 3];
  }
  __shared__ float red[256][4];
  red[tid][0] = a0; red[tid][1] = a1; red[tid][2] = a2; red[tid][3] = a3;
  __syncthreads();
  for (int s = 128; s > 0; s >>= 1) {
    if (tid < s) {
      red[tid][0] += red[tid + s][0]; red[tid][1] += red[tid + s][1];
      red[tid][2] += red[tid + s][2]; red[tid][3] += red[tid + s][3];
    }
    __syncthreads();
  }
  if (tid < 4) out[b * 4 + tid] = red[0][tid] + bias[tid];
}

// ---------------------------------------------------------------------------
extern "C" void kernel_launch(void* const* d_in, const int* in_sizes, int n_in,
                              void* d_out, int out_size, void* d_ws, size_t ws_size,
                              hipStream_t stream)
{
  const float* x   = (const float*)d_in[0];
  const float* Wx1 = (const float*)d_in[1];
  const float* Wh1 = (const float*)d_in[2];
  const float* b1  = (const float*)d_in[3];
  const float* Wx2 = (const float*)d_in[4];
  const float* Wh2 = (const float*)d_in[5];
  const float* b2  = (const float*)d_in[6];
  const float* Wx3 = (const float*)d_in[7];
  const float* Wh3 = (const float*)d_in[8];
  const float* b3  = (const float*)d_in[9];
  const float* Wd1 = (const float*)d_in[10];
  const float* bd1 = (const float*)d_in[11];
  const float* Wd2 = (const float*)d_in[12];
  const float* bd2 = (const float*)d_in[13];
  const float* Wd3 = (const float*)d_in[14];
  const float* bd3 = (const float*)d_in[15];

  char* ws = (char*)d_ws;
  size_t off = 0;
  auto alloc = [&](size_t bytes) -> void* {
    void* p = ws + off;
    off += (bytes + 255) & ~(size_t)255;
    return p;
  };
  bf16* x_bf = (bf16*)alloc((size_t)1966080 * 2);
  bf16* wx1t = (bf16*)alloc((size_t)64000 * 2);     // [512][125]
  bf16* wh1t = (bf16*)alloc((size_t)1638400 * 2);   // [512][3200]
  bf16* wx2t = (bf16*)alloc((size_t)819200 * 2);    // [256][3200]
  bf16* wh2t = (bf16*)alloc((size_t)409600 * 2);    // [256][1600]
  bf16* wx3t = (bf16*)alloc((size_t)409600 * 2);    // [256][1600]
  bf16* wh3t = (bf16*)alloc((size_t)409600 * 2);    // [256][1600]
  bf16* xzA  = (bf16*)alloc((size_t)176947200 * 2); // xz1 (354MB) | xz2 | xz3
  bf16* hB   = (bf16*)alloc((size_t)44236800 * 2);  // h1seq | h2seq
  float* hzC = (float*)alloc((size_t)29491200 * 4); // hz1 (118MB) | hz2 | hz3
  float* cA  = (float*)alloc((size_t)7372800 * 4);  // c1 | (c2,c3)
  float* h3f = (float*)alloc((size_t)2768896 * 4);
  bf16* hpadA = (bf16*)alloc((size_t)8388608 * 2);  // hpad1 | (hpad2,hpad3)
  float* part = (float*)alloc((size_t)256 * 16384 * 4);  // dense partials (16MB)
  float* z1   = (float*)alloc(16384 * 4);
  float* z2   = (float*)alloc(16384 * 4);

  bf16* h1seq = hB;
  bf16* h2seq = hB;                       // h1seq dead once xz2 built
  float* c1 = cA;
  float* c2 = cA;                         // c1 dead after layer 1
  float* c3 = cA + (size_t)3211264;
  bf16* hpad1 = hpadA;                    // [16][64][64][128]
  bf16* hpad2 = hpadA;                    // [16][60][60][64], after layer 1
  bf16* hpad3 = hpadA + (size_t)3686400;  // [16][56][56][64]

  // ---- weight/input casts ----
  cast_f32_bf16<<<(1966080 + 255) / 256, 256, 0, stream>>>(x, x_bf, 1966080);
  cast_transpose<<<(64000 + 255) / 256, 256, 0, stream>>>(Wx1, wx1t, 125, 512);
  cast_transpose<<<(1638400 + 255) / 256, 256, 0, stream>>>(Wh1, wh1t, 3200, 512);
  cast_transpose<<<(819200 + 255) / 256, 256, 0, stream>>>(Wx2, wx2t, 3200, 256);
  cast_transpose<<<(409600 + 255) / 256, 256, 0, stream>>>(Wh2, wh2t, 1600, 256);
  cast_transpose<<<(409600 + 255) / 256, 256, 0, stream>>>(Wx3, wx3t, 1600, 256);
  cast_transpose<<<(409600 + 255) / 256, 256, 0, stream>>>(Wh3, wh3t, 1600, 256);

  // ---- layer 1: 64x64x5 -> 60x60x128, N=512 ----
  hipMemsetAsync(hpadA, 0, (size_t)8388608 * 2, stream);  // zero halo (whole buf)
  conv_gemm64<5><<<dim3(5400, 8), 256, 0, stream>>>(
      x_bf, wx1t, b1, xzA, 3600, 60, 64, 64, 512, 125);
  for (int t = 0; t < 6; ++t) {
    if (t > 0)
      conv_gemm256<128, 7><<<dim3(2, 225), 512, 0, stream>>>(
          hpad1, wh1t, nullptr, xzA, nullptr, hzC,
          3600, 60, 64, 64, 6, t, 512, 3200, 1);
    gate_kernel<<<28800, 256, 0, stream>>>(
        xzA, (t > 0) ? hzC : nullptr, c1, h1seq,
        (t < 5) ? hpad1 : nullptr, nullptr,
        3600, 60, 64, 4096, 128, t, 6, 7372800);
  }

  // ---- layer 2: 60x60x128 -> 56x56x64, N=256 ----
  bf16* xz2 = xzA;
  conv_gemm256<128, 7><<<dim3(1, 1176), 512, 0, stream>>>(
      h1seq, wx2t, b2, nullptr, xz2, nullptr,
      3136, 56, 60, 60, 6, 0, 256, 3200, 0);
  hipMemsetAsync(hpad2, 0, (size_t)3686400 * 2, stream);
  for (int t = 0; t < 6; ++t) {
    if (t > 0)
      conv_gemm256<64, 6><<<dim3(1, 196), 512, 0, stream>>>(
          hpad2, wh2t, nullptr, xz2, nullptr, hzC,
          3136, 56, 60, 60, 6, t, 256, 1600, 1);
    gate_kernel<<<12544, 256, 0, stream>>>(
        xz2, (t > 0) ? hzC : nullptr, c2, h2seq,
        (t < 5) ? hpad2 : nullptr, nullptr,
        3136, 56, 60, 3600, 64, t, 6, 3211264);
  }

  // ---- layer 3: 56x56x64 -> 52x52x64, N=256, return last h only ----
  bf16* xz3 = xzA;
  conv_gemm256<64, 6><<<dim3(1, 1014), 512, 0, stream>>>(
      h2seq, wx3t, b3, nullptr, xz3, nullptr,
      2704, 52, 56, 56, 6, 0, 256, 1600, 0);
  hipMemsetAsync(hpad3, 0, (size_t)3211264 * 2, stream);
  for (int t = 0; t < 6; ++t) {
    if (t > 0)
      conv_gemm256<64, 6><<<dim3(1, 169), 512, 0, stream>>>(
          hpad3, wh3t, nullptr, xz3, nullptr, hzC,
          2704, 52, 56, 56, 6, t, 256, 1600, 1);
    gate_kernel<<<10816, 256, 0, stream>>>(
        xz3, (t > 0) ? hzC : nullptr, c3, nullptr,
        (t < 5) ? hpad3 : nullptr, (t == 5) ? h3f : nullptr,
        2704, 52, 56, 3136, 64, t, 6, 2768896);
  }

  // ---- dense head (fp32) ----
  // layer 1: D=173056 = 256 blocks x 676 rows (1 block/CU, balanced)
  dense_stage1<<<256, 256, 0, stream>>>(h3f, Wd1, part, 173056, 676);
  dense_reduce<<<64, 256, 0, stream>>>(part, bd1, z1, 256);
  // layer 2: D=1024 = 16 blocks x 64 rows
  dense_stage1<<<16, 256, 0, stream>>>(z1, Wd2, part, 1024, 64);
  dense_reduce<<<64, 256, 0, stream>>>(part, bd2, z2, 16);
  dense3_kernel<<<16, 256, 0, stream>>>(z2, Wd3, bd3, (float*)d_out);
}